// Round 7
// baseline (5804.617 us; speedup 1.0000x reference)
//
#include <hip/hip_runtime.h>
#include <hip/hip_bf16.h>

#define B_   2
#define T_   2048
#define HID_ 2048
#define H_   16
#define KVH_ 4
#define D_   128
#define GQ_  (H_ / KVH_)

typedef unsigned short u16;

// 8-byte-aligned group of 4 bf16 values for vector loads/stores.
struct __align__(8) us4 { u16 x, y, z, w; };

__device__ __forceinline__ float bf2f(u16 u) {
  return __uint_as_float(((unsigned)u) << 16);
}
__device__ __forceinline__ u16 f2bf(float f) {
  unsigned x = __float_as_uint(f);
  return (u16)((x + 0x7fffu + ((x >> 16) & 1u)) >> 16);  // RNE
}

// ---------------------------------------------------------------------------
// On-device dtype probe (bf16 vs fp32), per tensor. Reads 256 u16s at u16
// offset 16384 (in-bounds for every tensor here under either dtype).
// fp32 data seen as bf16: ~half the probed u16s are low-mantissa bits ->
// ~80% implausible values -> cX ~100 >= 8 -> fp32. Genuine bf16: cX ~ 0.
// fp32 upcast-from-bf16 (low mantissa zero): even u16s all 0 -> zX >= 100.
// Deterministic, wave-uniform exit -> graph-capture safe.
// ---------------------------------------------------------------------------
__device__ __forceinline__ void probe2(const void* A, const void* W, int tid,
                                       bool* abf, bool* wbf) {
  __shared__ int cA, zA, cW, zW;
  if (tid == 0) { cA = 0; zA = 0; cW = 0; zW = 0; }
  __syncthreads();
  const int i = 16384 + tid;  // u16 index; parity(i) == parity(tid)
  {
    const u16 raw = ((const u16*)A)[i];
    const float v = bf2f(raw);
    const bool bad = !(fabsf(v) <= 1e6f) ||            // NaN/inf/huge
                     (v != 0.0f && fabsf(v) < 1e-10f); // denormal-tiny
    if (bad) atomicAdd(&cA, 1);
    if (((tid & 1) == 0) && raw == 0) atomicAdd(&zA, 1);
  }
  {
    const u16 raw = ((const u16*)W)[i];
    const float v = bf2f(raw);
    const bool bad = !(fabsf(v) <= 1e6f) ||
                     (v != 0.0f && fabsf(v) < 1e-10f);
    if (bad) atomicAdd(&cW, 1);
    if (((tid & 1) == 0) && raw == 0) atomicAdd(&zW, 1);
  }
  __syncthreads();
  *abf = (cA < 8) && (zA < 100);
  *wbf = (cW < 8) && (zW < 100);
}

// ---------------------------------------------------------------------------
// GEMM: C[M,N] = A[M,K] @ W[K,N]; A,W bf16 OR fp32 row-major (auto-probed),
// fp32 compute. OUT_BF16 selects C dtype. 64x64 tile, 256 thr, 4x4
// micro-tile, BK=16. A staged transposed so both inner-loop LDS reads are
// float4 (row stride 68 floats = 272 B = 17*16 -> always 16B-aligned).
// ---------------------------------------------------------------------------
template <bool OUT_BF16>
__global__ __launch_bounds__(256) void gemm_any(const void* __restrict__ Av,
                                                const void* __restrict__ Wv_,
                                                void* __restrict__ Cv,
                                                int M, int N, int K) {
  const int tid = threadIdx.x;
  bool abf, wbf;
  probe2(Av, Wv_, tid, &abf, &wbf);

  __shared__ float As[16][64 + 4];   // As[k][m]
  __shared__ float Bs[16][64 + 4];   // Bs[k][n]
  const int tx = tid & 15;           // n-dir
  const int ty = tid >> 4;           // m-dir
  const int m0 = blockIdx.y * 64;
  const int n0 = blockIdx.x * 64;

  float acc[4][4] = {};

  for (int k0 = 0; k0 < K; k0 += 16) {
    {
      const int r = tid >> 2;              // 0..63  (m)
      const int c = (tid & 3) * 4;         // 0,4,8,12 (k)
      const size_t off = (size_t)(m0 + r) * K + k0 + c;  // multiple of 4
      float4 a4;
      if (abf) {
        const us4 t = *(const us4*)((const u16*)Av + off);
        a4 = make_float4(bf2f(t.x), bf2f(t.y), bf2f(t.z), bf2f(t.w));
      } else {
        a4 = *(const float4*)((const float*)Av + off);
      }
      As[c + 0][r] = a4.x;
      As[c + 1][r] = a4.y;
      As[c + 2][r] = a4.z;
      As[c + 3][r] = a4.w;
    }
    {
      const int r = tid >> 4;              // 0..15 (k)
      const int c = (tid & 15) * 4;        // 0..60 (n)
      const size_t off = (size_t)(k0 + r) * N + n0 + c;
      float4 b4;
      if (wbf) {
        const us4 t = *(const us4*)((const u16*)Wv_ + off);
        b4 = make_float4(bf2f(t.x), bf2f(t.y), bf2f(t.z), bf2f(t.w));
      } else {
        b4 = *(const float4*)((const float*)Wv_ + off);
      }
      Bs[r][c + 0] = b4.x;
      Bs[r][c + 1] = b4.y;
      Bs[r][c + 2] = b4.z;
      Bs[r][c + 3] = b4.w;
    }
    __syncthreads();

#pragma unroll
    for (int kk = 0; kk < 16; ++kk) {
      const float4 a = *(const float4*)&As[kk][ty * 4];
      const float4 b = *(const float4*)&Bs[kk][tx * 4];
      const float av[4] = {a.x, a.y, a.z, a.w};
      const float bv[4] = {b.x, b.y, b.z, b.w};
#pragma unroll
      for (int i = 0; i < 4; ++i)
#pragma unroll
        for (int j = 0; j < 4; ++j) acc[i][j] += av[i] * bv[j];
    }
    __syncthreads();
  }

  if (OUT_BF16) {
    u16* C = (u16*)Cv;
#pragma unroll
    for (int i = 0; i < 4; ++i) {
      us4 o4 = {f2bf(acc[i][0]), f2bf(acc[i][1]), f2bf(acc[i][2]),
                f2bf(acc[i][3])};
      *(us4*)&C[(size_t)(m0 + ty * 4 + i) * N + n0 + tx * 4] = o4;
    }
  } else {
    float* C = (float*)Cv;
#pragma unroll
    for (int i = 0; i < 4; ++i) {
      float4 o4 = {acc[i][0], acc[i][1], acc[i][2], acc[i][3]};
      *(float4*)&C[(size_t)(m0 + ty * 4 + i) * N + n0 + tx * 4] = o4;
    }
  }
}

// ---------------------------------------------------------------------------
// RoPE (rotate-half), in place on a fp32 (B, T, NH, D) workspace tensor.
// cos/sin tables bf16 OR fp32 (auto-probed). Exact grids (no partial
// blocks), so the probe's barriers are safe.
// ---------------------------------------------------------------------------
__global__ __launch_bounds__(256) void rope_k(float* __restrict__ t,
                                              const void* __restrict__ cosT,
                                              const void* __restrict__ sinT,
                                              int NH, int total) {
  const int tid = threadIdx.x;
  bool cbf, sbf;
  probe2(cosT, sinT, tid, &cbf, &sbf);

  const int idx = blockIdx.x * blockDim.x + tid;
  if (idx >= total) return;                  // never taken (exact grids)
  const int d = idx & 63;
  const int rest = idx >> 6;                 // (b*T + t)*NH + h
  const int tt = (rest / NH) % T_;
  const size_t base = (size_t)rest * D_;
  const int ci = tt * D_ + d;
  float c1, s1, c2, s2;
  if (cbf) {
    c1 = bf2f(((const u16*)cosT)[ci]);
    c2 = bf2f(((const u16*)cosT)[ci + 64]);
  } else {
    c1 = ((const float*)cosT)[ci];
    c2 = ((const float*)cosT)[ci + 64];
  }
  if (sbf) {
    s1 = bf2f(((const u16*)sinT)[ci]);
    s2 = bf2f(((const u16*)sinT)[ci + 64]);
  } else {
    s1 = ((const float*)sinT)[ci];
    s2 = ((const float*)sinT)[ci + 64];
  }
  const float x1 = t[base + d];
  const float x2 = t[base + d + 64];
  t[base + d] = x1 * c1 - x2 * s1;
  t[base + d + 64] = x2 * c2 + x1 * s2;
}

// ---------------------------------------------------------------------------
// Causal GQA flash attention. q,k,v fp32 workspace; o bf16 workspace.
// One block = one (b,h) x 32-query tile; online softmax; each thread owns
// 1 query row x 16 of D=128.
// ---------------------------------------------------------------------------
__global__ __launch_bounds__(256) void attn_k(const float* __restrict__ q,
                                              const float* __restrict__ k,
                                              const float* __restrict__ v,
                                              u16* __restrict__ o) {
  const float scale = 0.08838834764831845f;  // 1/sqrt(128)
  const float NEG = -1.0e30f;
  const int tid = threadIdx.x;
  const int qt = blockIdx.x;                 // 0..T/32-1
  const int bh = blockIdx.y;                 // 0..B*H-1
  const int b = bh / H_;
  const int h = bh % H_;
  const int kvh = h / GQ_;
  const int q0 = qt * 32;

  __shared__ float Qs[32][D_ + 1];
  __shared__ float Ks[32][D_ + 1];
  __shared__ float Vs[32][D_ + 1];
  __shared__ float Ss[32][33];
  __shared__ float mrow[32], lrow[32], arow[32];

  for (int i4 = tid; i4 < 32 * (D_ / 4); i4 += 256) {
    const int r = i4 >> 5;
    const int c = (i4 & 31) * 4;
    const float4 q4 =
        *(const float4*)&q[((((size_t)b * T_ + q0 + r) * H_) + h) * D_ + c];
    Qs[r][c + 0] = q4.x * scale;
    Qs[r][c + 1] = q4.y * scale;
    Qs[r][c + 2] = q4.z * scale;
    Qs[r][c + 3] = q4.w * scale;
  }
  if (tid < 32) {
    mrow[tid] = NEG;
    lrow[tid] = 0.0f;
  }

  const int qrow = tid >> 3;    // 0..31
  const int dseg = tid & 7;     // 0..7 (16 floats each)
  float acc[16] = {};

  const int nkt = qt + 1;       // causal: only tiles up to the diagonal
  for (int kt = 0; kt < nkt; ++kt) {
    const int k0 = kt * 32;
    __syncthreads();  // prev PV done (and Q/m/l ready on first iter)
    for (int i4 = tid; i4 < 32 * (D_ / 4); i4 += 256) {
      const int r = i4 >> 5;
      const int c = (i4 & 31) * 4;
      const size_t gi = ((((size_t)b * T_ + k0 + r) * KVH_) + kvh) * D_ + c;
      const float4 k4 = *(const float4*)&k[gi];
      const float4 v4 = *(const float4*)&v[gi];
      Ks[r][c + 0] = k4.x; Ks[r][c + 1] = k4.y;
      Ks[r][c + 2] = k4.z; Ks[r][c + 3] = k4.w;
      Vs[r][c + 0] = v4.x; Vs[r][c + 1] = v4.y;
      Vs[r][c + 2] = v4.z; Vs[r][c + 3] = v4.w;
    }
    __syncthreads();

    {
      const int qq = tid >> 3;
      const int kb = (tid & 7) * 4;
#pragma unroll
      for (int j = 0; j < 4; ++j) {
        const int kkk = kb + j;
        const float* qp = Qs[qq];
        const float* kp = Ks[kkk];
        float s = 0.0f;
#pragma unroll 8
        for (int d = 0; d < D_; ++d) s += qp[d] * kp[d];
        if (q0 + qq < k0 + kkk) s = NEG;  // causal mask
        Ss[qq][kkk] = s;
      }
    }
    __syncthreads();

    if (tid < 32) {
      const float m_old = mrow[tid];
      float mx = m_old;
#pragma unroll
      for (int j = 0; j < 32; ++j) mx = fmaxf(mx, Ss[tid][j]);
      const float a = __expf(m_old - mx);
      float l = lrow[tid] * a;
#pragma unroll
      for (int j = 0; j < 32; ++j) {
        const float p = __expf(Ss[tid][j] - mx);
        Ss[tid][j] = p;
        l += p;
      }
      mrow[tid] = mx;
      lrow[tid] = l;
      arow[tid] = a;
    }
    __syncthreads();

    {
      const float a = arow[qrow];
#pragma unroll
      for (int e = 0; e < 16; ++e) acc[e] *= a;
#pragma unroll 4
      for (int kkk = 0; kkk < 32; ++kkk) {
        const float p = Ss[qrow][kkk];
        const float* vp = &Vs[kkk][dseg * 16];
#pragma unroll
        for (int e = 0; e < 16; ++e) acc[e] += p * vp[e];
      }
    }
  }

  const float linv = 1.0f / lrow[qrow];
#pragma unroll
  for (int e = 0; e < 16; ++e) {
    o[((((size_t)b * T_ + q0 + qrow) * H_) + h) * D_ + dseg * 16 + e] =
        f2bf(acc[e] * linv);
  }
}

// Fallback: zero d_out (fp32) so an undersized workspace fails cleanly.
__global__ void zero_out_k(float* __restrict__ out, int n) {
  const int i = blockIdx.x * blockDim.x + threadIdx.x;
  if (i < n) out[i] = 0.0f;
}

// ---------------------------------------------------------------------------
extern "C" void kernel_launch(void* const* d_in, const int* in_sizes, int n_in,
                              void* d_out, int out_size, void* d_ws,
                              size_t ws_size, hipStream_t stream) {
  // Dtype map (evidence R0-R6): inputs MIXED bf16/fp32 -> probed on device
  // per tensor (probe2). Output FP32 (= reference's output dtype per the
  // harness contract; R6's finite-but-wrong absmax matches bf16-written-
  // into-fp32-buffer readback garbage).
  const void* x    = d_in[0];
  const void* cosT = d_in[1];
  const void* sinT = d_in[2];
  const void* Wq   = d_in[3];
  const void* Wk   = d_in[4];
  const void* Wv   = d_in[5];
  const void* Wo   = d_in[6];
  float* out = (float*)d_out;

  // Workspace: qbuf fp32 32MiB | kbuf fp32 8MiB | vbuf fp32 8MiB |
  //            obuf bf16 16MiB  -> 64 MiB total (R5/R6 proved this fits).
  const size_t QN = (size_t)B_ * T_ * H_ * D_;     // 8388608
  const size_t KN = (size_t)B_ * T_ * KVH_ * D_;   // 2097152
  const size_t need = (QN + 2 * KN) * sizeof(float) + QN * sizeof(u16);
  if (ws_size < need) {
    zero_out_k<<<(out_size + 255) / 256, 256, 0, stream>>>(out, out_size);
    return;
  }

  float* qbuf = (float*)d_ws;
  float* kbuf = qbuf + QN;
  float* vbuf = kbuf + KN;
  u16*   obuf = (u16*)(vbuf + KN);

  const int M = B_ * T_;  // 4096
  dim3 blk(256);

  gemm_any<false><<<dim3((H_ * D_) / 64, M / 64), blk, 0, stream>>>(
      x, Wq, qbuf, M, H_ * D_, HID_);
  gemm_any<false><<<dim3((KVH_ * D_) / 64, M / 64), blk, 0, stream>>>(
      x, Wk, kbuf, M, KVH_ * D_, HID_);
  gemm_any<false><<<dim3((KVH_ * D_) / 64, M / 64), blk, 0, stream>>>(
      x, Wv, vbuf, M, KVH_ * D_, HID_);

  const int totq = B_ * T_ * H_ * (D_ / 2);   // 4194304 = 16384 * 256
  rope_k<<<totq / 256, blk, 0, stream>>>(qbuf, cosT, sinT, H_, totq);
  const int totk = B_ * T_ * KVH_ * (D_ / 2); // 1048576 = 4096 * 256
  rope_k<<<totk / 256, blk, 0, stream>>>(kbuf, cosT, sinT, KVH_, totk);

  attn_k<<<dim3(T_ / 32, B_ * H_), blk, 0, stream>>>(qbuf, kbuf, vbuf, obuf);

  // Final GEMM: A = obuf (genuine bf16, probe detects), C = FP32 d_out.
  gemm_any<false><<<dim3(HID_ / 64, M / 64), blk, 0, stream>>>(
      obuf, Wo, out, M, HID_, H_ * D_);
}

// Round 8
// 2424.090 us; speedup vs baseline: 2.3946x; 2.3946x over previous
//
#include <hip/hip_runtime.h>
#include <hip/hip_bf16.h>

#define B_   2
#define T_   2048
#define HID_ 2048
#define H_   16
#define KVH_ 4
#define D_   128
#define GQ_  (H_ / KVH_)

typedef unsigned short u16;
typedef __attribute__((ext_vector_type(8))) unsigned short us8v;

// 8-byte-aligned group of 4 bf16 values for vector loads/stores.
struct __align__(8) us4 { u16 x, y, z, w; };

__device__ __forceinline__ float bf2f(u16 u) {
  return __uint_as_float(((unsigned)u) << 16);
}
__device__ __forceinline__ u16 f2bf(float f) {
  unsigned x = __float_as_uint(f);
  return (u16)((x + 0x7fffu + ((x >> 16) & 1u)) >> 16);  // RNE
}

// ---------------------------------------------------------------------------
// On-device dtype probe (bf16 vs fp32), per tensor — unchanged from R7
// (inputs are a MIXED bf16/fp32 set; this resolved it). Wave-uniform,
// deterministic, graph-capture safe.
// ---------------------------------------------------------------------------
__device__ __forceinline__ void probe2(const void* A, const void* W, int tid,
                                       bool* abf, bool* wbf) {
  __shared__ int cA, zA, cW, zW;
  if (tid == 0) { cA = 0; zA = 0; cW = 0; zW = 0; }
  __syncthreads();
  const int i = 16384 + tid;
  {
    const u16 raw = ((const u16*)A)[i];
    const float v = bf2f(raw);
    const bool bad = !(fabsf(v) <= 1e6f) ||
                     (v != 0.0f && fabsf(v) < 1e-10f);
    if (bad) atomicAdd(&cA, 1);
    if (((tid & 1) == 0) && raw == 0) atomicAdd(&zA, 1);
  }
  {
    const u16 raw = ((const u16*)W)[i];
    const float v = bf2f(raw);
    const bool bad = !(fabsf(v) <= 1e6f) ||
                     (v != 0.0f && fabsf(v) < 1e-10f);
    if (bad) atomicAdd(&cW, 1);
    if (((tid & 1) == 0) && raw == 0) atomicAdd(&zW, 1);
  }
  __syncthreads();
  *abf = (cA < 8) && (zA < 100);
  *wbf = (cW < 8) && (zW < 100);
}

// ---------------------------------------------------------------------------
// GEMM: C[M,N] = A[M,K] @ W[K,N]; A,W bf16 OR fp32 (auto-probed), fp32
// compute. OUT_BF16 selects C dtype. 64x64 tile, 256 thr, 4x4 micro, BK=16.
// ---------------------------------------------------------------------------
template <bool OUT_BF16>
__global__ __launch_bounds__(256) void gemm_any(const void* __restrict__ Av,
                                                const void* __restrict__ Wv_,
                                                void* __restrict__ Cv,
                                                int M, int N, int K) {
  const int tid = threadIdx.x;
  bool abf, wbf;
  probe2(Av, Wv_, tid, &abf, &wbf);

  __shared__ float As[16][64 + 4];
  __shared__ float Bs[16][64 + 4];
  const int tx = tid & 15;
  const int ty = tid >> 4;
  const int m0 = blockIdx.y * 64;
  const int n0 = blockIdx.x * 64;

  float acc[4][4] = {};

  for (int k0 = 0; k0 < K; k0 += 16) {
    {
      const int r = tid >> 2;
      const int c = (tid & 3) * 4;
      const size_t off = (size_t)(m0 + r) * K + k0 + c;
      float4 a4;
      if (abf) {
        const us4 t = *(const us4*)((const u16*)Av + off);
        a4 = make_float4(bf2f(t.x), bf2f(t.y), bf2f(t.z), bf2f(t.w));
      } else {
        a4 = *(const float4*)((const float*)Av + off);
      }
      As[c + 0][r] = a4.x;
      As[c + 1][r] = a4.y;
      As[c + 2][r] = a4.z;
      As[c + 3][r] = a4.w;
    }
    {
      const int r = tid >> 4;
      const int c = (tid & 15) * 4;
      const size_t off = (size_t)(k0 + r) * N + n0 + c;
      float4 b4;
      if (wbf) {
        const us4 t = *(const us4*)((const u16*)Wv_ + off);
        b4 = make_float4(bf2f(t.x), bf2f(t.y), bf2f(t.z), bf2f(t.w));
      } else {
        b4 = *(const float4*)((const float*)Wv_ + off);
      }
      Bs[r][c + 0] = b4.x;
      Bs[r][c + 1] = b4.y;
      Bs[r][c + 2] = b4.z;
      Bs[r][c + 3] = b4.w;
    }
    __syncthreads();

#pragma unroll
    for (int kk = 0; kk < 16; ++kk) {
      const float4 a = *(const float4*)&As[kk][ty * 4];
      const float4 b = *(const float4*)&Bs[kk][tx * 4];
      const float av[4] = {a.x, a.y, a.z, a.w};
      const float bv[4] = {b.x, b.y, b.z, b.w};
#pragma unroll
      for (int i = 0; i < 4; ++i)
#pragma unroll
        for (int j = 0; j < 4; ++j) acc[i][j] += av[i] * bv[j];
    }
    __syncthreads();
  }

  if (OUT_BF16) {
    u16* C = (u16*)Cv;
#pragma unroll
    for (int i = 0; i < 4; ++i) {
      us4 o4 = {f2bf(acc[i][0]), f2bf(acc[i][1]), f2bf(acc[i][2]),
                f2bf(acc[i][3])};
      *(us4*)&C[(size_t)(m0 + ty * 4 + i) * N + n0 + tx * 4] = o4;
    }
  } else {
    float* C = (float*)Cv;
#pragma unroll
    for (int i = 0; i < 4; ++i) {
      float4 o4 = {acc[i][0], acc[i][1], acc[i][2], acc[i][3]};
      *(float4*)&C[(size_t)(m0 + ty * 4 + i) * N + n0 + tx * 4] = o4;
    }
  }
}

// ---------------------------------------------------------------------------
// RoPE (rotate-half), in place on a BF16 (B, T, NH, D) workspace tensor.
// cos/sin tables bf16 OR fp32 (auto-probed).
// ---------------------------------------------------------------------------
__global__ __launch_bounds__(256) void rope_bf(u16* __restrict__ t,
                                               const void* __restrict__ cosT,
                                               const void* __restrict__ sinT,
                                               int NH, int total) {
  const int tid = threadIdx.x;
  bool cbf, sbf;
  probe2(cosT, sinT, tid, &cbf, &sbf);

  const int idx = blockIdx.x * blockDim.x + tid;
  if (idx >= total) return;
  const int d = idx & 63;
  const int rest = idx >> 6;
  const int tt = (rest / NH) % T_;
  const size_t base = (size_t)rest * D_;
  const int ci = tt * D_ + d;
  float c1, s1, c2, s2;
  if (cbf) {
    c1 = bf2f(((const u16*)cosT)[ci]);
    c2 = bf2f(((const u16*)cosT)[ci + 64]);
  } else {
    c1 = ((const float*)cosT)[ci];
    c2 = ((const float*)cosT)[ci + 64];
  }
  if (sbf) {
    s1 = bf2f(((const u16*)sinT)[ci]);
    s2 = bf2f(((const u16*)sinT)[ci + 64]);
  } else {
    s1 = ((const float*)sinT)[ci];
    s2 = ((const float*)sinT)[ci + 64];
  }
  const float x1 = bf2f(t[base + d]);
  const float x2 = bf2f(t[base + d + 64]);
  t[base + d] = f2bf(x1 * c1 - x2 * s1);
  t[base + d + 64] = f2bf(x2 * c2 + x1 * s2);
}

// ---------------------------------------------------------------------------
// Causal GQA flash attention v2 (bf16 I/O, fp32 math).
// Block = 256 thr = one (b,h) x 64-query tile. K-tiles of 64. LDS bf16
// staged with XOR swizzle (granule g of 8 elems stored at g^((r>>2)&7)) so
// every hot read pattern is <=2-way bank-aliased (free). Scores: 4x4
// micro-tile per thread, ds_read_b128 feeding 32 FMAs each. Online softmax
// via 4-lane shfl groups. PV: float4 P + bf16 V granules, acc[4][8]/thread.
// ---------------------------------------------------------------------------
#define SROW 68  // Sx row stride (fp32): 16B-aligned, bank-step 4
__global__ __launch_bounds__(256, 2) void attn2(const u16* __restrict__ q,
                                                const u16* __restrict__ k,
                                                const u16* __restrict__ v,
                                                u16* __restrict__ o) {
  const float scale = 0.08838834764831845f;  // 1/sqrt(128)
  const float NEG = -1.0e30f;
  const int tid = threadIdx.x;
  const int qt = blockIdx.x;                 // 0..T/64-1
  const int bh = blockIdx.y;
  const int b = bh >> 4;
  const int h = bh & 15;
  const int kvh = h >> 2;                    // GQ_=4
  const int q0 = qt * 64;

  __shared__ __align__(16) u16 Qs[64 * 128];
  __shared__ __align__(16) u16 Ks[64 * 128];
  __shared__ __align__(16) u16 Vs[64 * 128];
  __shared__ __align__(16) float Sx[64 * SROW];
  __shared__ float mrow[64], lrow[64], arow[64];

  // ---- stage Q (64 rows x 16 granules of 8 bf16), swizzled ----
  for (int it = tid; it < 1024; it += 256) {
    const int r = it >> 4;
    const int g = it & 15;
    const us8v val =
        *(const us8v*)&q[((size_t)(b * T_ + q0 + r) * H_ + h) * D_ + g * 8];
    *(us8v*)&Qs[r * 128 + ((g ^ ((r >> 2) & 7)) << 3)] = val;
  }
  if (tid < 64) {
    mrow[tid] = NEG;
    lrow[tid] = 0.0f;
  }

  const int tq = tid >> 4;   // 0..15: rows 4tq..4tq+3
  const int tk = tid & 15;   // scores: cols 4tk..4tk+3; PV: granule tk
  float acc[4][8] = {};

  const int nkt = qt + 1;
  for (int kt = 0; kt < nkt; ++kt) {
    const int k0 = kt * 64;
    // ---- stage K,V tile ----
    for (int it = tid; it < 1024; it += 256) {
      const int r = it >> 4;
      const int g = it & 15;
      const size_t src =
          ((size_t)(b * T_ + k0 + r) * KVH_ + kvh) * D_ + g * 8;
      const int dst = r * 128 + ((g ^ ((r >> 2) & 7)) << 3);
      *(us8v*)&Ks[dst] = *(const us8v*)&k[src];
      *(us8v*)&Vs[dst] = *(const us8v*)&v[src];
    }
    __syncthreads();

    // ---- scores: S[4tq+i][4tk+j] over D=128 ----
    {
      float s[4][4] = {};
#pragma unroll
      for (int dc = 0; dc < 16; ++dc) {
        float qf[4][8], kf[4][8];
#pragma unroll
        for (int i = 0; i < 4; ++i) {
          const int r = 4 * tq + i;
          const us8v t8 = *(const us8v*)&Qs[r * 128 + ((dc ^ (tq & 7)) << 3)];
#pragma unroll
          for (int e = 0; e < 8; ++e) qf[i][e] = bf2f(t8[e]);
        }
#pragma unroll
        for (int j = 0; j < 4; ++j) {
          const int r = 4 * tk + j;
          const us8v t8 = *(const us8v*)&Ks[r * 128 + ((dc ^ (tk & 7)) << 3)];
#pragma unroll
          for (int e = 0; e < 8; ++e) kf[j][e] = bf2f(t8[e]);
        }
#pragma unroll
        for (int i = 0; i < 4; ++i)
#pragma unroll
          for (int j = 0; j < 4; ++j)
#pragma unroll
            for (int e = 0; e < 8; ++e) s[i][j] += qf[i][e] * kf[j][e];
      }
#pragma unroll
      for (int i = 0; i < 4; ++i) {
        float4 o4;
        float* po = (float*)&o4;
#pragma unroll
        for (int j = 0; j < 4; ++j) {
          float val = s[i][j] * scale;
          if (q0 + 4 * tq + i < k0 + 4 * tk + j) val = NEG;
          po[j] = val;
        }
        *(float4*)&Sx[(4 * tq + i) * SROW + 4 * tk] = o4;
      }
    }
    __syncthreads();

    // ---- online softmax: row r = tid>>2, 16 cols per lane ----
    {
      const int r = tid >> 2;
      const int qq = tid & 3;
      float* row = &Sx[r * SROW + qq * 16];
      float4 c0 = *(float4*)&row[0];
      float4 c1 = *(float4*)&row[4];
      float4 c2 = *(float4*)&row[8];
      float4 c3 = *(float4*)&row[12];
      float mx = fmaxf(fmaxf(fmaxf(c0.x, c0.y), fmaxf(c0.z, c0.w)),
                       fmaxf(fmaxf(c1.x, c1.y), fmaxf(c1.z, c1.w)));
      mx = fmaxf(mx, fmaxf(fmaxf(c2.x, c2.y), fmaxf(c2.z, c2.w)));
      mx = fmaxf(mx, fmaxf(fmaxf(c3.x, c3.y), fmaxf(c3.z, c3.w)));
      mx = fmaxf(mx, __shfl_xor(mx, 1));
      mx = fmaxf(mx, __shfl_xor(mx, 2));
      const float mold = mrow[r];
      const float mnew = fmaxf(mold, mx);
      c0.x = __expf(c0.x - mnew); c0.y = __expf(c0.y - mnew);
      c0.z = __expf(c0.z - mnew); c0.w = __expf(c0.w - mnew);
      c1.x = __expf(c1.x - mnew); c1.y = __expf(c1.y - mnew);
      c1.z = __expf(c1.z - mnew); c1.w = __expf(c1.w - mnew);
      c2.x = __expf(c2.x - mnew); c2.y = __expf(c2.y - mnew);
      c2.z = __expf(c2.z - mnew); c2.w = __expf(c2.w - mnew);
      c3.x = __expf(c3.x - mnew); c3.y = __expf(c3.y - mnew);
      c3.z = __expf(c3.z - mnew); c3.w = __expf(c3.w - mnew);
      float sum = (c0.x + c0.y + c0.z + c0.w) + (c1.x + c1.y + c1.z + c1.w) +
                  (c2.x + c2.y + c2.z + c2.w) + (c3.x + c3.y + c3.z + c3.w);
      sum += __shfl_xor(sum, 1);
      sum += __shfl_xor(sum, 2);
      const float al = __expf(mold - mnew);
      if (qq == 0) {
        mrow[r] = mnew;
        lrow[r] = lrow[r] * al + sum;
        arow[r] = al;
      }
      *(float4*)&row[0] = c0;
      *(float4*)&row[4] = c1;
      *(float4*)&row[8] = c2;
      *(float4*)&row[12] = c3;
    }
    __syncthreads();

    // ---- PV: acc[i][e] (rows 4tq+i, cols 8tk+e) ----
    {
      float al[4];
#pragma unroll
      for (int i = 0; i < 4; ++i) al[i] = arow[4 * tq + i];
#pragma unroll
      for (int i = 0; i < 4; ++i)
#pragma unroll
        for (int e = 0; e < 8; ++e) acc[i][e] *= al[i];
#pragma unroll
      for (int kc = 0; kc < 16; ++kc) {  // k-rows 4kc..4kc+3
        float4 p[4];
#pragma unroll
        for (int i = 0; i < 4; ++i)
          p[i] = *(float4*)&Sx[(4 * tq + i) * SROW + 4 * kc];
        float vf[4][8];
#pragma unroll
        for (int c = 0; c < 4; ++c) {
          const int r = 4 * kc + c;
          const us8v t8 = *(const us8v*)&Vs[r * 128 + ((tk ^ (kc & 7)) << 3)];
#pragma unroll
          for (int e = 0; e < 8; ++e) vf[c][e] = bf2f(t8[e]);
        }
#pragma unroll
        for (int i = 0; i < 4; ++i) {
          const float* pi = (const float*)&p[i];
#pragma unroll
          for (int c = 0; c < 4; ++c)
#pragma unroll
            for (int e = 0; e < 8; ++e) acc[i][e] += pi[c] * vf[c][e];
        }
      }
    }
    __syncthreads();
  }

  // ---- epilogue: out = acc / l, bf16 ----
#pragma unroll
  for (int i = 0; i < 4; ++i) {
    const float linv = 1.0f / lrow[4 * tq + i];
    us8v w;
#pragma unroll
    for (int e = 0; e < 8; ++e) w[e] = f2bf(acc[i][e] * linv);
    *(us8v*)&o[((size_t)(b * T_ + q0 + 4 * tq + i) * H_ + h) * D_ + 8 * tk] =
        w;
  }
}

// Fallback: zero d_out (fp32) so an undersized workspace fails cleanly.
__global__ void zero_out_k(float* __restrict__ out, int n) {
  const int i = blockIdx.x * blockDim.x + threadIdx.x;
  if (i < n) out[i] = 0.0f;
}

// ---------------------------------------------------------------------------
extern "C" void kernel_launch(void* const* d_in, const int* in_sizes, int n_in,
                              void* d_out, int out_size, void* d_ws,
                              size_t ws_size, hipStream_t stream) {
  const void* x    = d_in[0];
  const void* cosT = d_in[1];
  const void* sinT = d_in[2];
  const void* Wq   = d_in[3];
  const void* Wk   = d_in[4];
  const void* Wv   = d_in[5];
  const void* Wo   = d_in[6];
  float* out = (float*)d_out;

  // Workspace (bf16): qbuf 16MiB | kbuf 4MiB | vbuf 4MiB | obuf 16MiB = 40MiB
  const size_t QN = (size_t)B_ * T_ * H_ * D_;     // 8388608
  const size_t KN = (size_t)B_ * T_ * KVH_ * D_;   // 2097152
  const size_t need = (2 * QN + 2 * KN) * sizeof(u16);
  if (ws_size < need) {
    zero_out_k<<<(out_size + 255) / 256, 256, 0, stream>>>(out, out_size);
    return;
  }

  u16* qbuf = (u16*)d_ws;
  u16* kbuf = qbuf + QN;
  u16* vbuf = kbuf + KN;
  u16* obuf = vbuf + KN;

  const int M = B_ * T_;  // 4096
  dim3 blk(256);

  gemm_any<true><<<dim3((H_ * D_) / 64, M / 64), blk, 0, stream>>>(
      x, Wq, qbuf, M, H_ * D_, HID_);
  gemm_any<true><<<dim3((KVH_ * D_) / 64, M / 64), blk, 0, stream>>>(
      x, Wk, kbuf, M, KVH_ * D_, HID_);
  gemm_any<true><<<dim3((KVH_ * D_) / 64, M / 64), blk, 0, stream>>>(
      x, Wv, vbuf, M, KVH_ * D_, HID_);

  const int totq = B_ * T_ * H_ * (D_ / 2);   // 4194304
  rope_bf<<<totq / 256, blk, 0, stream>>>(qbuf, cosT, sinT, H_, totq);
  const int totk = B_ * T_ * KVH_ * (D_ / 2); // 1048576
  rope_bf<<<totk / 256, blk, 0, stream>>>(kbuf, cosT, sinT, KVH_, totk);

  attn2<<<dim3(T_ / 64, B_ * H_), blk, 0, stream>>>(qbuf, kbuf, vbuf, obuf);

  gemm_any<false><<<dim3(HID_ / 64, M / 64), blk, 0, stream>>>(
      obuf, Wo, out, M, HID_, H_ * D_);
}

// Round 9
// 1689.807 us; speedup vs baseline: 3.4351x; 1.4345x over previous
//
#include <hip/hip_runtime.h>
#include <hip/hip_bf16.h>

#define B_   2
#define T_   2048
#define HID_ 2048
#define H_   16
#define KVH_ 4
#define D_   128
#define GQ_  (H_ / KVH_)

typedef unsigned short u16;
typedef __attribute__((ext_vector_type(8))) unsigned short us8v;
typedef __attribute__((ext_vector_type(8))) short s16x8;   // MFMA A/B frag
typedef __attribute__((ext_vector_type(4))) float f32x4;   // MFMA C/D frag

struct __align__(8) us4 { u16 x, y, z, w; };

__device__ __forceinline__ float bf2f(u16 u) {
  return __uint_as_float(((unsigned)u) << 16);
}
__device__ __forceinline__ u16 f2bf(float f) {
  unsigned x = __float_as_uint(f);
  return (u16)((x + 0x7fffu + ((x >> 16) & 1u)) >> 16);  // RNE
}

// ---------------------------------------------------------------------------
// On-device dtype probe (bf16 vs fp32), per tensor — R7-proven on this
// mixed-dtype input set. Wave-uniform, deterministic, graph-capture safe.
// ---------------------------------------------------------------------------
__device__ __forceinline__ void probe2(const void* A, const void* W, int tid,
                                       bool* abf, bool* wbf) {
  __shared__ int cA, zA, cW, zW;
  if (tid == 0) { cA = 0; zA = 0; cW = 0; zW = 0; }
  __syncthreads();
  const int i = 16384 + tid;
  {
    const u16 raw = ((const u16*)A)[i];
    const float v = bf2f(raw);
    const bool bad = !(fabsf(v) <= 1e6f) ||
                     (v != 0.0f && fabsf(v) < 1e-10f);
    if (bad) atomicAdd(&cA, 1);
    if (((tid & 1) == 0) && raw == 0) atomicAdd(&zA, 1);
  }
  {
    const u16 raw = ((const u16*)W)[i];
    const float v = bf2f(raw);
    const bool bad = !(fabsf(v) <= 1e6f) ||
                     (v != 0.0f && fabsf(v) < 1e-10f);
    if (bad) atomicAdd(&cW, 1);
    if (((tid & 1) == 0) && raw == 0) atomicAdd(&zW, 1);
  }
  __syncthreads();
  *abf = (cA < 8) && (zA < 100);
  *wbf = (cW < 8) && (zW < 100);
}

// ---------------------------------------------------------------------------
// Transpose W[K][N] (bf16 OR fp32, probed) -> WT[N][K] bf16. Runs once per
// weight; makes GEMM B-staging k-contiguous (required by MFMA B-fragment).
// fp32 LDS tile with +1 pad: both phases conflict-free; scalar LDS ops only.
// ---------------------------------------------------------------------------
__global__ __launch_bounds__(256) void transp_k(const void* __restrict__ Wv_,
                                                u16* __restrict__ WT,
                                                int K, int N) {
  const int tid = threadIdx.x;
  bool wbf, dummy;
  probe2(Wv_, Wv_, tid, &wbf, &dummy);

  __shared__ float tile[64][65];
  const int kb = blockIdx.y * 64;
  const int nb = blockIdx.x * 64;

  for (int it = tid; it < 512; it += 256) {
    const int r = it >> 3;            // k-row 0..63
    const int g = it & 7;             // n-granule
    const size_t off = (size_t)(kb + r) * N + nb + g * 8;
    float f[8];
    if (wbf) {
      const us8v t8 = *(const us8v*)((const u16*)Wv_ + off);
#pragma unroll
      for (int e = 0; e < 8; ++e) f[e] = bf2f(t8[e]);
    } else {
      const float4 f0 = *(const float4*)((const float*)Wv_ + off);
      const float4 f1 = *(const float4*)((const float*)Wv_ + off + 4);
      f[0] = f0.x; f[1] = f0.y; f[2] = f0.z; f[3] = f0.w;
      f[4] = f1.x; f[5] = f1.y; f[6] = f1.z; f[7] = f1.w;
    }
#pragma unroll
    for (int e = 0; e < 8; ++e) tile[r][g * 8 + e] = f[e];
  }
  __syncthreads();
  for (int it = tid; it < 512; it += 256) {
    const int n = it >> 3;            // 0..63
    const int g = it & 7;             // k-granule
    us8v tmp;
#pragma unroll
    for (int e = 0; e < 8; ++e) tmp[e] = f2bf(tile[g * 8 + e][n]);
    *(us8v*)&WT[(size_t)(nb + n) * K + kb + g * 8] = tmp;
  }
}

// ---------------------------------------------------------------------------
// MFMA GEMM: C[M,N] = A[M,K] @ W[K,N], W given pre-transposed (WT[N][K],
// bf16). A bf16 OR fp32 (probed). 128x128 tile, 4 waves (2x2), each wave
// 4x4 tiles of v_mfma_f32_16x16x32_bf16, BK=32.
// Frag layouts (m89/m91-verified): A[m=lane&15][k=quad*8+j],
// B[k=quad*8+j][n=lane&15], D col=lane&15, row=quad*4+reg.
// LDS row stride 40 elems (80 B): 16B-aligned, 2-way bank alias (free).
// ---------------------------------------------------------------------------
template <bool OUT_BF16>
__global__ __launch_bounds__(256) void gemm_mfma(const void* __restrict__ Av,
                                                 const u16* __restrict__ WT,
                                                 void* __restrict__ Cv,
                                                 int M, int N, int K) {
  const int tid = threadIdx.x;
  bool abf, dummy;
  probe2(Av, Av, tid, &abf, &dummy);

  __shared__ __align__(16) u16 Alds[128 * 40];
  __shared__ __align__(16) u16 Blds[128 * 40];

  const int m0 = blockIdx.y * 128;
  const int n0 = blockIdx.x * 128;
  const int wave = tid >> 6;
  const int lane = tid & 63;
  const int wm = (wave >> 1) * 64;
  const int wn = (wave & 1) * 64;
  const int lrow = lane & 15;
  const int lq = lane >> 4;

  f32x4 acc[4][4] = {};

  for (int k0 = 0; k0 < K; k0 += 32) {
    // ---- stage A tile: 128 m-rows x 32 k (k-contiguous) ----
    for (int it = tid; it < 512; it += 256) {
      const int r = it >> 2;
      const int g = it & 3;
      const size_t off = (size_t)(m0 + r) * K + k0 + g * 8;
      us8v tmp;
      if (abf) {
        tmp = *(const us8v*)((const u16*)Av + off);
      } else {
        const float4 f0 = *(const float4*)((const float*)Av + off);
        const float4 f1 = *(const float4*)((const float*)Av + off + 4);
        tmp[0] = f2bf(f0.x); tmp[1] = f2bf(f0.y);
        tmp[2] = f2bf(f0.z); tmp[3] = f2bf(f0.w);
        tmp[4] = f2bf(f1.x); tmp[5] = f2bf(f1.y);
        tmp[6] = f2bf(f1.z); tmp[7] = f2bf(f1.w);
      }
      *(us8v*)&Alds[r * 40 + g * 8] = tmp;
    }
    // ---- stage B tile: 128 n-rows x 32 k from WT (k-contiguous) ----
    for (int it = tid; it < 512; it += 256) {
      const int n = it >> 2;
      const int g = it & 3;
      *(us8v*)&Blds[n * 40 + g * 8] =
          *(const us8v*)&WT[(size_t)(n0 + n) * K + k0 + g * 8];
    }
    __syncthreads();

    s16x8 af[4], bfr[4];
#pragma unroll
    for (int mi = 0; mi < 4; ++mi)
      af[mi] = *(const s16x8*)&Alds[(wm + 16 * mi + lrow) * 40 + lq * 8];
#pragma unroll
    for (int ni = 0; ni < 4; ++ni)
      bfr[ni] = *(const s16x8*)&Blds[(wn + 16 * ni + lrow) * 40 + lq * 8];
#pragma unroll
    for (int mi = 0; mi < 4; ++mi)
#pragma unroll
      for (int ni = 0; ni < 4; ++ni)
        acc[mi][ni] = __builtin_amdgcn_mfma_f32_16x16x32_bf16(
            af[mi], bfr[ni], acc[mi][ni], 0, 0, 0);
    __syncthreads();
  }

  // ---- epilogue: D col=lane&15, row=quad*4+reg ----
#pragma unroll
  for (int mi = 0; mi < 4; ++mi) {
#pragma unroll
    for (int ni = 0; ni < 4; ++ni) {
      const int row0 = m0 + wm + 16 * mi + lq * 4;
      const int col = n0 + wn + 16 * ni + lrow;
#pragma unroll
      for (int r = 0; r < 4; ++r) {
        if (OUT_BF16)
          ((u16*)Cv)[(size_t)(row0 + r) * N + col] = f2bf(acc[mi][ni][r]);
        else
          ((float*)Cv)[(size_t)(row0 + r) * N + col] = acc[mi][ni][r];
      }
    }
  }
}

// ---------------------------------------------------------------------------
// RoPE (rotate-half), in place on a BF16 (B, T, NH, D) workspace tensor.
// cos/sin tables bf16 OR fp32 (auto-probed).
// ---------------------------------------------------------------------------
__global__ __launch_bounds__(256) void rope_bf(u16* __restrict__ t,
                                               const void* __restrict__ cosT,
                                               const void* __restrict__ sinT,
                                               int NH, int total) {
  const int tid = threadIdx.x;
  bool cbf, sbf;
  probe2(cosT, sinT, tid, &cbf, &sbf);

  const int idx = blockIdx.x * blockDim.x + tid;
  if (idx >= total) return;
  const int d = idx & 63;
  const int rest = idx >> 6;
  const int tt = (rest / NH) % T_;
  const size_t base = (size_t)rest * D_;
  const int ci = tt * D_ + d;
  float c1, s1, c2, s2;
  if (cbf) {
    c1 = bf2f(((const u16*)cosT)[ci]);
    c2 = bf2f(((const u16*)cosT)[ci + 64]);
  } else {
    c1 = ((const float*)cosT)[ci];
    c2 = ((const float*)cosT)[ci + 64];
  }
  if (sbf) {
    s1 = bf2f(((const u16*)sinT)[ci]);
    s2 = bf2f(((const u16*)sinT)[ci + 64]);
  } else {
    s1 = ((const float*)sinT)[ci];
    s2 = ((const float*)sinT)[ci + 64];
  }
  const float x1 = bf2f(t[base + d]);
  const float x2 = bf2f(t[base + d + 64]);
  t[base + d] = f2bf(x1 * c1 - x2 * s1);
  t[base + d + 64] = f2bf(x2 * c2 + x1 * s2);
}

// ---------------------------------------------------------------------------
// Causal GQA flash attention v2 (bf16 I/O, fp32 math) — unchanged from R8.
// ---------------------------------------------------------------------------
#define SROW 68
__global__ __launch_bounds__(256, 2) void attn2(const u16* __restrict__ q,
                                                const u16* __restrict__ k,
                                                const u16* __restrict__ v,
                                                u16* __restrict__ o) {
  const float scale = 0.08838834764831845f;  // 1/sqrt(128)
  const float NEG = -1.0e30f;
  const int tid = threadIdx.x;
  const int qt = blockIdx.x;
  const int bh = blockIdx.y;
  const int b = bh >> 4;
  const int h = bh & 15;
  const int kvh = h >> 2;
  const int q0 = qt * 64;

  __shared__ __align__(16) u16 Qs[64 * 128];
  __shared__ __align__(16) u16 Ks[64 * 128];
  __shared__ __align__(16) u16 Vs[64 * 128];
  __shared__ __align__(16) float Sx[64 * SROW];
  __shared__ float mrow[64], lrow[64], arow[64];

  for (int it = tid; it < 1024; it += 256) {
    const int r = it >> 4;
    const int g = it & 15;
    const us8v val =
        *(const us8v*)&q[((size_t)(b * T_ + q0 + r) * H_ + h) * D_ + g * 8];
    *(us8v*)&Qs[r * 128 + ((g ^ ((r >> 2) & 7)) << 3)] = val;
  }
  if (tid < 64) {
    mrow[tid] = NEG;
    lrow[tid] = 0.0f;
  }

  const int tq = tid >> 4;
  const int tk = tid & 15;
  float acc[4][8] = {};

  const int nkt = qt + 1;
  for (int kt = 0; kt < nkt; ++kt) {
    const int k0 = kt * 64;
    for (int it = tid; it < 1024; it += 256) {
      const int r = it >> 4;
      const int g = it & 15;
      const size_t src =
          ((size_t)(b * T_ + k0 + r) * KVH_ + kvh) * D_ + g * 8;
      const int dst = r * 128 + ((g ^ ((r >> 2) & 7)) << 3);
      *(us8v*)&Ks[dst] = *(const us8v*)&k[src];
      *(us8v*)&Vs[dst] = *(const us8v*)&v[src];
    }
    __syncthreads();

    {
      float s[4][4] = {};
#pragma unroll
      for (int dc = 0; dc < 16; ++dc) {
        float qf[4][8], kf[4][8];
#pragma unroll
        for (int i = 0; i < 4; ++i) {
          const int r = 4 * tq + i;
          const us8v t8 = *(const us8v*)&Qs[r * 128 + ((dc ^ (tq & 7)) << 3)];
#pragma unroll
          for (int e = 0; e < 8; ++e) qf[i][e] = bf2f(t8[e]);
        }
#pragma unroll
        for (int j = 0; j < 4; ++j) {
          const int r = 4 * tk + j;
          const us8v t8 = *(const us8v*)&Ks[r * 128 + ((dc ^ (tk & 7)) << 3)];
#pragma unroll
          for (int e = 0; e < 8; ++e) kf[j][e] = bf2f(t8[e]);
        }
#pragma unroll
        for (int i = 0; i < 4; ++i)
#pragma unroll
          for (int j = 0; j < 4; ++j)
#pragma unroll
            for (int e = 0; e < 8; ++e) s[i][j] += qf[i][e] * kf[j][e];
      }
#pragma unroll
      for (int i = 0; i < 4; ++i) {
        float4 o4;
        float* po = (float*)&o4;
#pragma unroll
        for (int j = 0; j < 4; ++j) {
          float val = s[i][j] * scale;
          if (q0 + 4 * tq + i < k0 + 4 * tk + j) val = NEG;
          po[j] = val;
        }
        *(float4*)&Sx[(4 * tq + i) * SROW + 4 * tk] = o4;
      }
    }
    __syncthreads();

    {
      const int r = tid >> 2;
      const int qq = tid & 3;
      float* row = &Sx[r * SROW + qq * 16];
      float4 c0 = *(float4*)&row[0];
      float4 c1 = *(float4*)&row[4];
      float4 c2 = *(float4*)&row[8];
      float4 c3 = *(float4*)&row[12];
      float mx = fmaxf(fmaxf(fmaxf(c0.x, c0.y), fmaxf(c0.z, c0.w)),
                       fmaxf(fmaxf(c1.x, c1.y), fmaxf(c1.z, c1.w)));
      mx = fmaxf(mx, fmaxf(fmaxf(c2.x, c2.y), fmaxf(c2.z, c2.w)));
      mx = fmaxf(mx, fmaxf(fmaxf(c3.x, c3.y), fmaxf(c3.z, c3.w)));
      mx = fmaxf(mx, __shfl_xor(mx, 1));
      mx = fmaxf(mx, __shfl_xor(mx, 2));
      const float mold = mrow[r];
      const float mnew = fmaxf(mold, mx);
      c0.x = __expf(c0.x - mnew); c0.y = __expf(c0.y - mnew);
      c0.z = __expf(c0.z - mnew); c0.w = __expf(c0.w - mnew);
      c1.x = __expf(c1.x - mnew); c1.y = __expf(c1.y - mnew);
      c1.z = __expf(c1.z - mnew); c1.w = __expf(c1.w - mnew);
      c2.x = __expf(c2.x - mnew); c2.y = __expf(c2.y - mnew);
      c2.z = __expf(c2.z - mnew); c2.w = __expf(c2.w - mnew);
      c3.x = __expf(c3.x - mnew); c3.y = __expf(c3.y - mnew);
      c3.z = __expf(c3.z - mnew); c3.w = __expf(c3.w - mnew);
      float sum = (c0.x + c0.y + c0.z + c0.w) + (c1.x + c1.y + c1.z + c1.w) +
                  (c2.x + c2.y + c2.z + c2.w) + (c3.x + c3.y + c3.z + c3.w);
      sum += __shfl_xor(sum, 1);
      sum += __shfl_xor(sum, 2);
      const float al = __expf(mold - mnew);
      if (qq == 0) {
        mrow[r] = mnew;
        lrow[r] = lrow[r] * al + sum;
        arow[r] = al;
      }
      *(float4*)&row[0] = c0;
      *(float4*)&row[4] = c1;
      *(float4*)&row[8] = c2;
      *(float4*)&row[12] = c3;
    }
    __syncthreads();

    {
      float al[4];
#pragma unroll
      for (int i = 0; i < 4; ++i) al[i] = arow[4 * tq + i];
#pragma unroll
      for (int i = 0; i < 4; ++i)
#pragma unroll
        for (int e = 0; e < 8; ++e) acc[i][e] *= al[i];
#pragma unroll
      for (int kc = 0; kc < 16; ++kc) {
        float4 p[4];
#pragma unroll
        for (int i = 0; i < 4; ++i)
          p[i] = *(float4*)&Sx[(4 * tq + i) * SROW + 4 * kc];
        float vf[4][8];
#pragma unroll
        for (int c = 0; c < 4; ++c) {
          const int r = 4 * kc + c;
          const us8v t8 = *(const us8v*)&Vs[r * 128 + ((tk ^ (kc & 7)) << 3)];
#pragma unroll
          for (int e = 0; e < 8; ++e) vf[c][e] = bf2f(t8[e]);
        }
#pragma unroll
        for (int i = 0; i < 4; ++i) {
          const float* pi = (const float*)&p[i];
#pragma unroll
          for (int c = 0; c < 4; ++c)
#pragma unroll
            for (int e = 0; e < 8; ++e) acc[i][e] += pi[c] * vf[c][e];
        }
      }
    }
    __syncthreads();
  }

#pragma unroll
  for (int i = 0; i < 4; ++i) {
    const float linv = 1.0f / lrow[4 * tq + i];
    us8v w;
#pragma unroll
    for (int e = 0; e < 8; ++e) w[e] = f2bf(acc[i][e] * linv);
    *(us8v*)&o[((size_t)(b * T_ + q0 + 4 * tq + i) * H_ + h) * D_ + 8 * tk] =
        w;
  }
}

// Fallback: zero d_out (fp32) so an undersized workspace fails cleanly.
__global__ void zero_out_k(float* __restrict__ out, int n) {
  const int i = blockIdx.x * blockDim.x + threadIdx.x;
  if (i < n) out[i] = 0.0f;
}

// ---------------------------------------------------------------------------
extern "C" void kernel_launch(void* const* d_in, const int* in_sizes, int n_in,
                              void* d_out, int out_size, void* d_ws,
                              size_t ws_size, hipStream_t stream) {
  const void* x    = d_in[0];
  const void* cosT = d_in[1];
  const void* sinT = d_in[2];
  const void* Wq   = d_in[3];
  const void* Wk   = d_in[4];
  const void* Wv   = d_in[5];
  const void* Wo   = d_in[6];
  float* out = (float*)d_out;

  // Workspace (bf16 elems): qbuf QN | kbuf KN | vbuf KN | obuf QN |
  //   WqT 4194304 | WkT 1048576 | WvT 1048576 | WoT 4194304  = 60 MiB.
  const size_t QN = (size_t)B_ * T_ * H_ * D_;     // 8388608
  const size_t KN = (size_t)B_ * T_ * KVH_ * D_;   // 2097152
  const size_t WQT = (size_t)HID_ * (H_ * D_);     // 4194304
  const size_t WKT = (size_t)HID_ * (KVH_ * D_);   // 1048576
  const size_t need = (2 * QN + 2 * KN + 2 * WQT + 2 * WKT) * sizeof(u16);
  if (ws_size < need) {
    zero_out_k<<<(out_size + 255) / 256, 256, 0, stream>>>(out, out_size);
    return;
  }

  u16* qbuf = (u16*)d_ws;
  u16* kbuf = qbuf + QN;
  u16* vbuf = kbuf + KN;
  u16* obuf = vbuf + KN;
  u16* WqT  = obuf + QN;
  u16* WkT  = WqT + WQT;
  u16* WvT  = WkT + WKT;
  u16* WoT  = WvT + WKT;

  const int M = B_ * T_;  // 4096
  dim3 blk(256);

  // One-time weight transposes (W[K][N] -> WT[N][K] bf16).
  transp_k<<<dim3((H_ * D_) / 64, HID_ / 64), blk, 0, stream>>>(
      Wq, WqT, HID_, H_ * D_);
  transp_k<<<dim3((KVH_ * D_) / 64, HID_ / 64), blk, 0, stream>>>(
      Wk, WkT, HID_, KVH_ * D_);
  transp_k<<<dim3((KVH_ * D_) / 64, HID_ / 64), blk, 0, stream>>>(
      Wv, WvT, HID_, KVH_ * D_);
  transp_k<<<dim3(HID_ / 64, (H_ * D_) / 64), blk, 0, stream>>>(
      Wo, WoT, H_ * D_, HID_);

  // Projections (MFMA).
  gemm_mfma<true><<<dim3((H_ * D_) / 128, M / 128), blk, 0, stream>>>(
      x, WqT, qbuf, M, H_ * D_, HID_);
  gemm_mfma<true><<<dim3((KVH_ * D_) / 128, M / 128), blk, 0, stream>>>(
      x, WkT, kbuf, M, KVH_ * D_, HID_);
  gemm_mfma<true><<<dim3((KVH_ * D_) / 128, M / 128), blk, 0, stream>>>(
      x, WvT, vbuf, M, KVH_ * D_, HID_);

  const int totq = B_ * T_ * H_ * (D_ / 2);   // 4194304
  rope_bf<<<totq / 256, blk, 0, stream>>>(qbuf, cosT, sinT, H_, totq);
  const int totk = B_ * T_ * KVH_ * (D_ / 2); // 1048576
  rope_bf<<<totk / 256, blk, 0, stream>>>(kbuf, cosT, sinT, KVH_, totk);

  attn2<<<dim3(T_ / 64, B_ * H_), blk, 0, stream>>>(qbuf, kbuf, vbuf, obuf);

  // Output projection (MFMA, fp32 out).
  gemm_mfma<false><<<dim3(HID_ / 128, M / 128), blk, 0, stream>>>(
      obuf, WoT, out, M, HID_, H_ * D_);
}